// Round 4
// baseline (480.646 us; speedup 1.0000x reference)
//
#include <hip/hip_runtime.h>
#include <math.h>

#define T_TOK 256
#define H_DIM 1024
#define E_NUM 64
#define I_DIM 512
#define SI_DIM 2048

#define BN 64
#define BM 32

typedef __attribute__((ext_vector_type(8))) short short8;
typedef __attribute__((ext_vector_type(8))) __bf16 bf16x8;
typedef __attribute__((ext_vector_type(4))) float floatx4;
typedef __attribute__((ext_vector_type(4))) unsigned short ushort4v;
typedef __attribute__((ext_vector_type(8))) unsigned short ushort8;

// float -> bf16 round-to-nearest-even
static __device__ __forceinline__ unsigned short f2bf(float f) {
  unsigned u = __float_as_uint(f);
  u += 0x7FFFu + ((u >> 16) & 1u);
  return (unsigned short)(u >> 16);
}

static __device__ __forceinline__ ushort4v pack4(floatx4 v) {
  ushort4v b;
  b[0] = f2bf(v[0]); b[1] = f2bf(v[1]); b[2] = f2bf(v[2]); b[3] = f2bf(v[3]);
  return b;
}

static __device__ __forceinline__ bf16x8 pack8(floatx4 a, floatx4 b) {
  ushort8 s;
  s[0] = f2bf(a[0]); s[1] = f2bf(a[1]); s[2] = f2bf(a[2]); s[3] = f2bf(a[3]);
  s[4] = f2bf(b[0]); s[5] = f2bf(b[1]); s[6] = f2bf(b[2]); s[7] = f2bf(b[3]);
  union { ushort8 u; bf16x8 v; } cv; cv.u = s;
  return cv.v;
}

static __device__ __forceinline__ floatx4 mfma16(bf16x8 a, bf16x8 b, floatx4 c) {
  return __builtin_amdgcn_mfma_f32_16x16x32_bf16(a, b, c, 0, 0, 0);
}

// ---------------------------------------------------------------------------
// Kernel 1: gate matmul (fp64, 4-way H-split) + noaux_tc routing + x->bf16.
// ---------------------------------------------------------------------------
__global__ __launch_bounds__(256) void gate_route_kernel(
    const float* __restrict__ x, const float* __restrict__ gw,
    const float* __restrict__ ebias, unsigned short* __restrict__ xbf,
    int* __restrict__ cnt, int* __restrict__ tok_list,
    float* __restrict__ wt_list) {
  const int t = blockIdx.x;
  const int j = threadIdx.x;
  __shared__ float xs[H_DIM];
  __shared__ double pd[4 * 64];

  floatx4 v = ((const floatx4*)(x + (size_t)t * H_DIM))[j];
  xs[4 * j + 0] = v[0]; xs[4 * j + 1] = v[1];
  xs[4 * j + 2] = v[2]; xs[4 * j + 3] = v[3];
  ((ushort4v*)(xbf + (size_t)t * H_DIM))[j] = pack4(v);
  __syncthreads();

  const int e = j & 63, ch = j >> 6;
  const float* wr = gw + (size_t)e * H_DIM + ch * 256;
  const float* xc = xs + ch * 256;
  double acc = 0.0;
  for (int i = 0; i < 64; ++i) {
    floatx4 w = ((const floatx4*)wr)[i];
    acc += (double)xc[4 * i + 0] * (double)w[0]
         + (double)xc[4 * i + 1] * (double)w[1]
         + (double)xc[4 * i + 2] * (double)w[2]
         + (double)xc[4 * i + 3] * (double)w[3];
  }
  pd[ch * 64 + e] = acc;
  __syncthreads();

  if (j < 64) {
    const int lane = j;
    const double logit = pd[lane] + pd[64 + lane] + pd[128 + lane] + pd[192 + lane];
    const double score = 1.0 / (1.0 + exp(-logit));
    const double swb = score + (double)ebias[lane];

    double m1 = swb, m2 = -1.0e300;
    #pragma unroll
    for (int d = 1; d < 8; d <<= 1) {
      double o1 = __shfl_xor(m1, d);
      double o2 = __shfl_xor(m2, d);
      double hi = fmax(m1, o1), lo = fmin(m1, o1);
      m1 = hi;
      m2 = fmax(lo, fmax(m2, o2));
    }
    const double gscore = m1 + m2;

    double gs[8];
    #pragma unroll
    for (int g = 0; g < 8; ++g) gs[g] = __shfl(gscore, g << 3);
    unsigned gsel = 0;
    #pragma unroll
    for (int it = 0; it < 4; ++it) {
      int best = 0; double bv = -1.0e300;
      #pragma unroll
      for (int g = 0; g < 8; ++g) {
        bool taken = (gsel >> g) & 1u;
        if (!taken && gs[g] > bv) { bv = gs[g]; best = g; }
      }
      gsel |= 1u << best;
    }

    double key = ((gsel >> (lane >> 3)) & 1u) ? swb : -1.0e300;
    int selected = 0;
    for (int it = 0; it < 6; ++it) {
      double vv = key; int idx = lane;
      #pragma unroll
      for (int d = 1; d < 64; d <<= 1) {
        double ov = __shfl_xor(vv, d);
        int oi = __shfl_xor(idx, d);
        if (ov > vv || (ov == vv && oi < idx)) { vv = ov; idx = oi; }
      }
      if (lane == idx) { selected = 1; key = -1.0e300; }
    }

    double ssum = selected ? score : 0.0;
    #pragma unroll
    for (int d = 1; d < 64; d <<= 1) ssum += __shfl_xor(ssum, d);

    if (selected) {
      float wgt = (float)(score / (ssum + 1e-20) * 2.5);
      int p = atomicAdd(&cnt[lane], 1);
      tok_list[lane * T_TOK + p] = t;
      wt_list[lane * T_TOK + p] = wgt;
    }
  }
}

// ---------------------------------------------------------------------------
// Kernel 2: routed gate/up. Weights have zero reuse -> stream them directly
// global->reg->pack->MFMA (lane(q,c) loads exactly its B-fragment:
// row n0+wv*16+c, k in [kc+8q, +8) = 2x dwordx4). A-token-tile staged in
// swizzled LDS in two 512-col K-halves (32 KiB). Inner K-loop barrier-free;
// weight prefetch registers persist across the half boundary.
// ---------------------------------------------------------------------------
__global__ __launch_bounds__(256, 2) void routed_gu_kernel(
    const unsigned short* __restrict__ xbf, const float* __restrict__ w1,
    const float* __restrict__ w3, const int* __restrict__ cnt,
    const int* __restrict__ tok_list, unsigned short* __restrict__ act_r) {
  __shared__ __align__(16) char sAB[BM * 1024];  // 32 rows x 512 bf16, swizzled

  const int e = blockIdx.x >> 3;
  const int n0 = (blockIdx.x & 7) * BN;
  const int j = threadIdx.x;
  const int wv = j >> 6, lane = j & 63;
  const int q = lane >> 4, c = lane & 15;
  const int kq = q * 8;
  const int ne = cnt[e];
  if (ne <= 0) return;
  const int* tl = tok_list + e * T_TOK;
  unsigned short* ap = act_r + (size_t)e * T_TOK * I_DIM;

  const float* wgR = w1 + ((size_t)e * I_DIM + n0 + wv * 16 + c) * H_DIM;
  const float* wuR = w3 + ((size_t)e * I_DIM + n0 + wv * 16 + c) * H_DIM;

  const int sr = j >> 3, st8 = (j & 7) * 8;   // staging: 8 threads per row
  const int xrs = (sr & 7) << 4;
  const int xr0 = (c & 7) << 4;               // rows c and 16+c share (row&7)

  for (int m0 = 0; m0 < ne; m0 += BM) {
    const int tok = (m0 + sr < ne) ? tl[m0 + sr] : tl[m0];
    const unsigned short* aRow = xbf + (size_t)tok * H_DIM;

    floatx4 cg0 = *(const floatx4*)(wgR + kq);
    floatx4 cg1 = *(const floatx4*)(wgR + kq + 4);
    floatx4 cu0 = *(const floatx4*)(wuR + kq);
    floatx4 cu1 = *(const floatx4*)(wuR + kq + 4);

    floatx4 ag0 = (floatx4)0.0f, ag1 = (floatx4)0.0f;
    floatx4 au0 = (floatx4)0.0f, au1 = (floatx4)0.0f;

    for (int half = 0; half < 2; ++half) {
      const int kbase = half * 512;
      __syncthreads();  // prior readers of sAB done
      #pragma unroll
      for (int i = 0; i < 512; i += 64) {
        const int col = st8 + i;
        *(bf16x8*)(sAB + sr * 1024 + ((2 * col) ^ xrs)) =
            *(const bf16x8*)(aRow + kbase + col);
      }
      __syncthreads();
      for (int kcl = 0; kcl < 512; kcl += 32) {
        const int kc = kbase + kcl;
        bf16x8 bg = pack8(cg0, cg1);
        bf16x8 bu = pack8(cu0, cu1);
        if (kc + 32 < H_DIM) {  // prefetch next weight chunk (global, no LDS dep)
          cg0 = *(const floatx4*)(wgR + kc + 32 + kq);
          cg1 = *(const floatx4*)(wgR + kc + 32 + kq + 4);
          cu0 = *(const floatx4*)(wuR + kc + 32 + kq);
          cu1 = *(const floatx4*)(wuR + kc + 32 + kq + 4);
        }
        const int kb = 2 * (kcl + kq);
        bf16x8 a0 = *(const bf16x8*)(sAB + c * 1024 + (kb ^ xr0));
        bf16x8 a1 = *(const bf16x8*)(sAB + (16 + c) * 1024 + (kb ^ xr0));
        ag0 = mfma16(a0, bg, ag0);
        ag1 = mfma16(a1, bg, ag1);
        au0 = mfma16(a0, bu, au0);
        au1 = mfma16(a1, bu, au1);
      }
    }
    #pragma unroll
    for (int s = 0; s < 2; ++s) {
      floatx4 g = s ? ag1 : ag0;
      floatx4 u = s ? au1 : au0;
      #pragma unroll
      for (int r = 0; r < 4; ++r) {
        const int m = m0 + s * 16 + q * 4 + r;
        if (m < ne) {
          float gg = g[r], uu = u[r];
          float a = gg / (1.0f + __expf(-gg)) * uu;
          ap[(size_t)m * I_DIM + n0 + wv * 16 + c] = f2bf(a);
        }
      }
    }
  }
}

// ---------------------------------------------------------------------------
// Kernel 3: shared gate/up, same direct-stream structure (single m-tile).
// ---------------------------------------------------------------------------
__global__ __launch_bounds__(256, 2) void shared_gu_kernel(
    const unsigned short* __restrict__ xbf, const float* __restrict__ wsg,
    const float* __restrict__ wsu, unsigned short* __restrict__ act_s) {
  __shared__ __align__(16) char sAB[BM * 1024];

  const int n0 = (blockIdx.x & 31) * BN;
  const int m0 = (blockIdx.x >> 5) * BM;
  const int j = threadIdx.x;
  const int wv = j >> 6, lane = j & 63;
  const int q = lane >> 4, c = lane & 15;
  const int kq = q * 8;

  const float* wgR = wsg + (size_t)(n0 + wv * 16 + c) * H_DIM;
  const float* wuR = wsu + (size_t)(n0 + wv * 16 + c) * H_DIM;

  const int sr = j >> 3, st8 = (j & 7) * 8;
  const int xrs = (sr & 7) << 4;
  const int xr0 = (c & 7) << 4;
  const unsigned short* aRow = xbf + (size_t)(m0 + sr) * H_DIM;

  floatx4 cg0 = *(const floatx4*)(wgR + kq);
  floatx4 cg1 = *(const floatx4*)(wgR + kq + 4);
  floatx4 cu0 = *(const floatx4*)(wuR + kq);
  floatx4 cu1 = *(const floatx4*)(wuR + kq + 4);

  floatx4 ag0 = (floatx4)0.0f, ag1 = (floatx4)0.0f;
  floatx4 au0 = (floatx4)0.0f, au1 = (floatx4)0.0f;

  for (int half = 0; half < 2; ++half) {
    const int kbase = half * 512;
    __syncthreads();
    #pragma unroll
    for (int i = 0; i < 512; i += 64) {
      const int col = st8 + i;
      *(bf16x8*)(sAB + sr * 1024 + ((2 * col) ^ xrs)) =
          *(const bf16x8*)(aRow + kbase + col);
    }
    __syncthreads();
    for (int kcl = 0; kcl < 512; kcl += 32) {
      const int kc = kbase + kcl;
      bf16x8 bg = pack8(cg0, cg1);
      bf16x8 bu = pack8(cu0, cu1);
      if (kc + 32 < H_DIM) {
        cg0 = *(const floatx4*)(wgR + kc + 32 + kq);
        cg1 = *(const floatx4*)(wgR + kc + 32 + kq + 4);
        cu0 = *(const floatx4*)(wuR + kc + 32 + kq);
        cu1 = *(const floatx4*)(wuR + kc + 32 + kq + 4);
      }
      const int kb = 2 * (kcl + kq);
      bf16x8 a0 = *(const bf16x8*)(sAB + c * 1024 + (kb ^ xr0));
      bf16x8 a1 = *(const bf16x8*)(sAB + (16 + c) * 1024 + (kb ^ xr0));
      ag0 = mfma16(a0, bg, ag0);
      ag1 = mfma16(a1, bg, ag1);
      au0 = mfma16(a0, bu, au0);
      au1 = mfma16(a1, bu, au1);
    }
  }
  #pragma unroll
  for (int s = 0; s < 2; ++s) {
    floatx4 g = s ? ag1 : ag0;
    floatx4 u = s ? au1 : au0;
    #pragma unroll
    for (int r = 0; r < 4; ++r) {
      const int m = m0 + s * 16 + q * 4 + r;
      float gg = g[r], uu = u[r];
      float a = gg / (1.0f + __expf(-gg)) * uu;
      act_s[(size_t)m * SI_DIM + n0 + wv * 16 + c] = f2bf(a);
    }
  }
}

// ---------------------------------------------------------------------------
// Kernel 4: shared down; K-split x2 across blocks, two K-half stages each,
// atomicAdd into zeroed out.
// ---------------------------------------------------------------------------
__global__ __launch_bounds__(256, 2) void shared_down_kernel(
    const unsigned short* __restrict__ act_s, const float* __restrict__ wsd,
    float* __restrict__ out) {
  __shared__ __align__(16) char sAB[BM * 1024];

  const int n0 = (blockIdx.x & 15) * BN;
  const int m0 = ((blockIdx.x >> 4) & 7) * BM;
  const int kh = blockIdx.x >> 7;
  const int kbeg = kh * (SI_DIM / 2);
  const int j = threadIdx.x;
  const int wv = j >> 6, lane = j & 63;
  const int q = lane >> 4, c = lane & 15;
  const int kq = q * 8;

  const float* wR = wsd + (size_t)(n0 + wv * 16 + c) * SI_DIM + kbeg;

  const int sr = j >> 3, st8 = (j & 7) * 8;
  const int xrs = (sr & 7) << 4;
  const int xr0 = (c & 7) << 4;
  const unsigned short* aRow = act_s + (size_t)(m0 + sr) * SI_DIM + kbeg;

  floatx4 cw0 = *(const floatx4*)(wR + kq);
  floatx4 cw1 = *(const floatx4*)(wR + kq + 4);

  floatx4 ac0 = (floatx4)0.0f, ac1 = (floatx4)0.0f;
  for (int half = 0; half < 2; ++half) {
    const int kbase = half * 512;
    __syncthreads();
    #pragma unroll
    for (int i = 0; i < 512; i += 64) {
      const int col = st8 + i;
      *(bf16x8*)(sAB + sr * 1024 + ((2 * col) ^ xrs)) =
          *(const bf16x8*)(aRow + kbase + col);
    }
    __syncthreads();
    for (int kcl = 0; kcl < 512; kcl += 32) {
      const int kc = kbase + kcl;
      bf16x8 b = pack8(cw0, cw1);
      if (kc + 32 < SI_DIM / 2) {
        cw0 = *(const floatx4*)(wR + kc + 32 + kq);
        cw1 = *(const floatx4*)(wR + kc + 32 + kq + 4);
      }
      const int kb = 2 * (kcl + kq);
      bf16x8 a0 = *(const bf16x8*)(sAB + c * 1024 + (kb ^ xr0));
      bf16x8 a1 = *(const bf16x8*)(sAB + (16 + c) * 1024 + (kb ^ xr0));
      ac0 = mfma16(a0, b, ac0);
      ac1 = mfma16(a1, b, ac1);
    }
  }
  #pragma unroll
  for (int s = 0; s < 2; ++s) {
    floatx4 d = s ? ac1 : ac0;
    #pragma unroll
    for (int r = 0; r < 4; ++r) {
      const int m = m0 + s * 16 + q * 4 + r;
      atomicAdd(&out[(size_t)m * H_DIM + n0 + wv * 16 + c], d[r]);
    }
  }
}

// ---------------------------------------------------------------------------
// Kernel 5: routed down + weighted scatter-add, direct-stream (I=512 full-K,
// 32 KiB LDS, single stage per m-tile).
// ---------------------------------------------------------------------------
__global__ __launch_bounds__(256, 2) void routed_down_kernel(
    const unsigned short* __restrict__ act_r, const float* __restrict__ w2,
    const int* __restrict__ cnt, const int* __restrict__ tok_list,
    const float* __restrict__ wt_list, float* __restrict__ out) {
  __shared__ __align__(16) char sAB[BM * 1024];  // 32 x 512 bf16, swizzled

  const int e = blockIdx.x >> 4;
  const int n0 = (blockIdx.x & 15) * BN;
  const int j = threadIdx.x;
  const int wv = j >> 6, lane = j & 63;
  const int q = lane >> 4, c = lane & 15;
  const int kq = q * 8;
  const int ne = cnt[e];
  if (ne <= 0) return;
  const int* tl = tok_list + e * T_TOK;
  const float* wl = wt_list + e * T_TOK;
  const unsigned short* apb = act_r + (size_t)e * T_TOK * I_DIM;
  const float* wR = w2 + ((size_t)e * H_DIM + n0 + wv * 16 + c) * I_DIM;

  const int sr = j >> 3, st8 = (j & 7) * 8;
  const int xrs = (sr & 7) << 4;
  const int xr0 = (c & 7) << 4;

  for (int m0 = 0; m0 < ne; m0 += BM) {
    __syncthreads();
    {
      int ar = m0 + sr;
      if (ar >= ne) ar = m0;      // pad rows re-stage a valid row
      const unsigned short* aRow = apb + (size_t)ar * I_DIM;
      #pragma unroll
      for (int i = 0; i < I_DIM; i += 64) {
        const int col = st8 + i;
        *(bf16x8*)(sAB + sr * 1024 + ((2 * col) ^ xrs)) =
            *(const bf16x8*)(aRow + col);
      }
    }
    __syncthreads();

    floatx4 cw0 = *(const floatx4*)(wR + kq);
    floatx4 cw1 = *(const floatx4*)(wR + kq + 4);

    floatx4 ac0 = (floatx4)0.0f, ac1 = (floatx4)0.0f;
    for (int kc = 0; kc < I_DIM; kc += 32) {
      bf16x8 b = pack8(cw0, cw1);
      if (kc + 32 < I_DIM) {
        cw0 = *(const floatx4*)(wR + kc + 32 + kq);
        cw1 = *(const floatx4*)(wR + kc + 32 + kq + 4);
      }
      const int kb = 2 * (kc + kq);
      bf16x8 a0 = *(const bf16x8*)(sAB + c * 1024 + (kb ^ xr0));
      bf16x8 a1 = *(const bf16x8*)(sAB + (16 + c) * 1024 + (kb ^ xr0));
      ac0 = mfma16(a0, b, ac0);
      ac1 = mfma16(a1, b, ac1);
    }
    #pragma unroll
    for (int s = 0; s < 2; ++s) {
      floatx4 d = s ? ac1 : ac0;
      #pragma unroll
      for (int r = 0; r < 4; ++r) {
        const int mi = s * 16 + q * 4 + r;
        if (m0 + mi < ne) {
          atomicAdd(&out[(size_t)tl[m0 + mi] * H_DIM + n0 + wv * 16 + c],
                    d[r] * wl[m0 + mi]);
        }
      }
    }
  }
}

extern "C" void kernel_launch(void* const* d_in, const int* in_sizes, int n_in,
                              void* d_out, int out_size, void* d_ws, size_t ws_size,
                              hipStream_t stream) {
  const float* x   = (const float*)d_in[0];
  const float* gw  = (const float*)d_in[1];
  const float* eb  = (const float*)d_in[2];
  const float* w1  = (const float*)d_in[3];
  const float* w3  = (const float*)d_in[4];
  const float* w2  = (const float*)d_in[5];
  const float* wsg = (const float*)d_in[6];
  const float* wsu = (const float*)d_in[7];
  const float* wsd = (const float*)d_in[8];
  float* out = (float*)d_out;

  char* ws = (char*)d_ws;
  unsigned short* xbf   = (unsigned short*)(ws);                 // 512 KB
  unsigned short* act_s = (unsigned short*)(ws + 524288);        // 1 MB
  int*   cnt            = (int*)(ws + 1572864);                  // 256 B
  int*   tok            = (int*)(ws + 1573120);                  // 64 KB
  float* wt             = (float*)(ws + 1638656);                // 64 KB
  unsigned short* act_r = (unsigned short*)(ws + 1704192);       // 16.8 MB

  hipMemsetAsync(cnt, 0, E_NUM * sizeof(int), stream);
  hipMemsetAsync(out, 0, (size_t)T_TOK * H_DIM * sizeof(float), stream);
  gate_route_kernel<<<dim3(T_TOK), dim3(256), 0, stream>>>(x, gw, eb, xbf, cnt, tok, wt);
  routed_gu_kernel<<<dim3(E_NUM * (I_DIM / BN)), dim3(256), 0, stream>>>(xbf, w1, w3, cnt, tok, act_r);
  shared_gu_kernel<<<dim3((SI_DIM / BN) * (T_TOK / BM)), dim3(256), 0, stream>>>(xbf, wsg, wsu, act_s);
  shared_down_kernel<<<dim3((H_DIM / BN) * (T_TOK / BM) * 2), dim3(256), 0, stream>>>(act_s, wsd, out);
  routed_down_kernel<<<dim3(E_NUM * (H_DIM / BN)), dim3(256), 0, stream>>>(act_r, w2, cnt, tok, wt, out);
}

// Round 5
// 465.373 us; speedup vs baseline: 1.0328x; 1.0328x over previous
//
#include <hip/hip_runtime.h>
#include <math.h>

#define T_TOK 256
#define H_DIM 1024
#define E_NUM 64
#define I_DIM 512
#define SI_DIM 2048

#define BN 64
#define BM 32

typedef __attribute__((ext_vector_type(8))) short short8;
typedef __attribute__((ext_vector_type(8))) __bf16 bf16x8;
typedef __attribute__((ext_vector_type(4))) float floatx4;
typedef __attribute__((ext_vector_type(4))) unsigned short ushort4v;
typedef __attribute__((ext_vector_type(8))) unsigned short ushort8;

// float -> bf16 round-to-nearest-even
static __device__ __forceinline__ unsigned short f2bf(float f) {
  unsigned u = __float_as_uint(f);
  u += 0x7FFFu + ((u >> 16) & 1u);
  return (unsigned short)(u >> 16);
}

static __device__ __forceinline__ ushort4v pack4(floatx4 v) {
  ushort4v b;
  b[0] = f2bf(v[0]); b[1] = f2bf(v[1]); b[2] = f2bf(v[2]); b[3] = f2bf(v[3]);
  return b;
}

static __device__ __forceinline__ bf16x8 pack8(floatx4 a, floatx4 b) {
  ushort8 s;
  s[0] = f2bf(a[0]); s[1] = f2bf(a[1]); s[2] = f2bf(a[2]); s[3] = f2bf(a[3]);
  s[4] = f2bf(b[0]); s[5] = f2bf(b[1]); s[6] = f2bf(b[2]); s[7] = f2bf(b[3]);
  union { ushort8 u; bf16x8 v; } cv; cv.u = s;
  return cv.v;
}

static __device__ __forceinline__ floatx4 mfma16(bf16x8 a, bf16x8 b, floatx4 c) {
  return __builtin_amdgcn_mfma_f32_16x16x32_bf16(a, b, c, 0, 0, 0);
}

// ---------------------------------------------------------------------------
// Kernel 1: gate matmul (fp64, 4-way H-split) + noaux_tc routing + x->bf16.
// ---------------------------------------------------------------------------
__global__ __launch_bounds__(256) void gate_route_kernel(
    const float* __restrict__ x, const float* __restrict__ gw,
    const float* __restrict__ ebias, unsigned short* __restrict__ xbf,
    int* __restrict__ cnt, int* __restrict__ tok_list,
    float* __restrict__ wt_list) {
  const int t = blockIdx.x;
  const int j = threadIdx.x;
  __shared__ float xs[H_DIM];
  __shared__ double pd[4 * 64];

  floatx4 v = ((const floatx4*)(x + (size_t)t * H_DIM))[j];
  xs[4 * j + 0] = v[0]; xs[4 * j + 1] = v[1];
  xs[4 * j + 2] = v[2]; xs[4 * j + 3] = v[3];
  ((ushort4v*)(xbf + (size_t)t * H_DIM))[j] = pack4(v);
  __syncthreads();

  const int e = j & 63, ch = j >> 6;
  const float* wr = gw + (size_t)e * H_DIM + ch * 256;
  const float* xc = xs + ch * 256;
  double acc = 0.0;
  for (int i = 0; i < 64; ++i) {
    floatx4 w = ((const floatx4*)wr)[i];
    acc += (double)xc[4 * i + 0] * (double)w[0]
         + (double)xc[4 * i + 1] * (double)w[1]
         + (double)xc[4 * i + 2] * (double)w[2]
         + (double)xc[4 * i + 3] * (double)w[3];
  }
  pd[ch * 64 + e] = acc;
  __syncthreads();

  if (j < 64) {
    const int lane = j;
    const double logit = pd[lane] + pd[64 + lane] + pd[128 + lane] + pd[192 + lane];
    const double score = 1.0 / (1.0 + exp(-logit));
    const double swb = score + (double)ebias[lane];

    double m1 = swb, m2 = -1.0e300;
    #pragma unroll
    for (int d = 1; d < 8; d <<= 1) {
      double o1 = __shfl_xor(m1, d);
      double o2 = __shfl_xor(m2, d);
      double hi = fmax(m1, o1), lo = fmin(m1, o1);
      m1 = hi;
      m2 = fmax(lo, fmax(m2, o2));
    }
    const double gscore = m1 + m2;

    double gs[8];
    #pragma unroll
    for (int g = 0; g < 8; ++g) gs[g] = __shfl(gscore, g << 3);
    unsigned gsel = 0;
    #pragma unroll
    for (int it = 0; it < 4; ++it) {
      int best = 0; double bv = -1.0e300;
      #pragma unroll
      for (int g = 0; g < 8; ++g) {
        bool taken = (gsel >> g) & 1u;
        if (!taken && gs[g] > bv) { bv = gs[g]; best = g; }
      }
      gsel |= 1u << best;
    }

    double key = ((gsel >> (lane >> 3)) & 1u) ? swb : -1.0e300;
    int selected = 0;
    for (int it = 0; it < 6; ++it) {
      double vv = key; int idx = lane;
      #pragma unroll
      for (int d = 1; d < 64; d <<= 1) {
        double ov = __shfl_xor(vv, d);
        int oi = __shfl_xor(idx, d);
        if (ov > vv || (ov == vv && oi < idx)) { vv = ov; idx = oi; }
      }
      if (lane == idx) { selected = 1; key = -1.0e300; }
    }

    double ssum = selected ? score : 0.0;
    #pragma unroll
    for (int d = 1; d < 64; d <<= 1) ssum += __shfl_xor(ssum, d);

    if (selected) {
      float wgt = (float)(score / (ssum + 1e-20) * 2.5);
      int p = atomicAdd(&cnt[lane], 1);
      tok_list[lane * T_TOK + p] = t;
      wt_list[lane * T_TOK + p] = wgt;
    }
  }
}

// ---------------------------------------------------------------------------
// Kernel 2: routed gate/up, direct weight streaming with K-PHASE ROTATION.
// All blocks marching k=0..1024 in lockstep camps on ~1/8 of HBM channels
// (4 KB row stride => channel = row*16 + col-granule; row term mod 128 hits
// only multiples of 16). Rotating each block/wave's chunk order spreads the
// instantaneous column window across all granules -> full channel coverage.
// ---------------------------------------------------------------------------
__global__ __launch_bounds__(256, 2) void routed_gu_kernel(
    const unsigned short* __restrict__ xbf, const float* __restrict__ w1,
    const float* __restrict__ w3, const int* __restrict__ cnt,
    const int* __restrict__ tok_list, unsigned short* __restrict__ act_r) {
  __shared__ __align__(16) char sAB[BM * 1024];  // 32 rows x 512 bf16, swizzled

  const int bid = blockIdx.x;
  const int e = bid >> 3;
  const int n0 = (bid & 7) * BN;
  const int j = threadIdx.x;
  const int wv = j >> 6, lane = j & 63;
  const int q = lane >> 4, c = lane & 15;
  const int kq = q * 8;
  const int ne = cnt[e];
  if (ne <= 0) return;
  const int* tl = tok_list + e * T_TOK;
  unsigned short* ap = act_r + (size_t)e * T_TOK * I_DIM;

  const float* wgR = w1 + ((size_t)e * I_DIM + n0 + wv * 16 + c) * H_DIM;
  const float* wuR = w3 + ((size_t)e * I_DIM + n0 + wv * 16 + c) * H_DIM;

  const int sr = j >> 3, st8 = (j & 7) * 8;   // staging: 8 threads per row
  const int xrs = (sr & 7) << 4;
  const int xr0 = (c & 7) << 4;               // rows c and 16+c share (row&7)

  const int h0 = bid & 1;                     // per-block half order
  const int ph = ((bid * 5) + (wv * 7)) & 15; // per-wave chunk phase

  for (int m0 = 0; m0 < ne; m0 += BM) {
    const int tok = (m0 + sr < ne) ? tl[m0 + sr] : tl[m0];
    const unsigned short* aRow = xbf + (size_t)tok * H_DIM;

    // prologue: issue first (rotated) weight chunk; overlaps A staging
    floatx4 cg0, cg1, cu0, cu1;
    {
      const int kc = h0 * 512 + ph * 32;
      cg0 = *(const floatx4*)(wgR + kc + kq);
      cg1 = *(const floatx4*)(wgR + kc + kq + 4);
      cu0 = *(const floatx4*)(wuR + kc + kq);
      cu1 = *(const floatx4*)(wuR + kc + kq + 4);
    }

    floatx4 ag0 = (floatx4)0.0f, ag1 = (floatx4)0.0f;
    floatx4 au0 = (floatx4)0.0f, au1 = (floatx4)0.0f;

    for (int hh = 0; hh < 2; ++hh) {
      const int half = h0 ^ hh;
      const int kbase = half * 512;
      __syncthreads();  // prior readers of sAB done
      #pragma unroll
      for (int i = 0; i < 512; i += 64) {
        const int col = st8 + i;
        *(bf16x8*)(sAB + sr * 1024 + ((2 * col) ^ xrs)) =
            *(const bf16x8*)(aRow + kbase + col);
      }
      __syncthreads();
      for (int it = 0; it < 16; ++it) {
        bf16x8 bg = pack8(cg0, cg1);
        bf16x8 bu = pack8(cu0, cu1);
        if (hh == 0 || it < 15) {  // prefetch next rotated chunk (global only)
          const int nit = it + 1;
          const int kcn = (nit < 16) ? kbase + ((nit + ph) & 15) * 32
                                     : (half ^ 1) * 512 + ph * 32;
          cg0 = *(const floatx4*)(wgR + kcn + kq);
          cg1 = *(const floatx4*)(wgR + kcn + kq + 4);
          cu0 = *(const floatx4*)(wuR + kcn + kq);
          cu1 = *(const floatx4*)(wuR + kcn + kq + 4);
        }
        const int kcl = ((it + ph) & 15) * 32;
        const int kb = 2 * (kcl + kq);
        bf16x8 a0 = *(const bf16x8*)(sAB + c * 1024 + (kb ^ xr0));
        bf16x8 a1 = *(const bf16x8*)(sAB + (16 + c) * 1024 + (kb ^ xr0));
        ag0 = mfma16(a0, bg, ag0);
        ag1 = mfma16(a1, bg, ag1);
        au0 = mfma16(a0, bu, au0);
        au1 = mfma16(a1, bu, au1);
      }
    }
    #pragma unroll
    for (int s = 0; s < 2; ++s) {
      floatx4 g = s ? ag1 : ag0;
      floatx4 u = s ? au1 : au0;
      #pragma unroll
      for (int r = 0; r < 4; ++r) {
        const int m = m0 + s * 16 + q * 4 + r;
        if (m < ne) {
          float gg = g[r], uu = u[r];
          float a = gg / (1.0f + __expf(-gg)) * uu;
          ap[(size_t)m * I_DIM + n0 + wv * 16 + c] = f2bf(a);
        }
      }
    }
  }
}

// ---------------------------------------------------------------------------
// Kernel 3: shared gate/up, same rotated direct-stream (single m-tile).
// ---------------------------------------------------------------------------
__global__ __launch_bounds__(256, 2) void shared_gu_kernel(
    const unsigned short* __restrict__ xbf, const float* __restrict__ wsg,
    const float* __restrict__ wsu, unsigned short* __restrict__ act_s) {
  __shared__ __align__(16) char sAB[BM * 1024];

  const int bid = blockIdx.x;
  const int n0 = (bid & 31) * BN;
  const int m0 = (bid >> 5) * BM;
  const int j = threadIdx.x;
  const int wv = j >> 6, lane = j & 63;
  const int q = lane >> 4, c = lane & 15;
  const int kq = q * 8;

  const float* wgR = wsg + (size_t)(n0 + wv * 16 + c) * H_DIM;
  const float* wuR = wsu + (size_t)(n0 + wv * 16 + c) * H_DIM;

  const int sr = j >> 3, st8 = (j & 7) * 8;
  const int xrs = (sr & 7) << 4;
  const int xr0 = (c & 7) << 4;
  const unsigned short* aRow = xbf + (size_t)(m0 + sr) * H_DIM;

  const int h0 = bid & 1;
  const int ph = ((bid * 5) + (wv * 7)) & 15;

  floatx4 cg0, cg1, cu0, cu1;
  {
    const int kc = h0 * 512 + ph * 32;
    cg0 = *(const floatx4*)(wgR + kc + kq);
    cg1 = *(const floatx4*)(wgR + kc + kq + 4);
    cu0 = *(const floatx4*)(wuR + kc + kq);
    cu1 = *(const floatx4*)(wuR + kc + kq + 4);
  }

  floatx4 ag0 = (floatx4)0.0f, ag1 = (floatx4)0.0f;
  floatx4 au0 = (floatx4)0.0f, au1 = (floatx4)0.0f;

  for (int hh = 0; hh < 2; ++hh) {
    const int half = h0 ^ hh;
    const int kbase = half * 512;
    __syncthreads();
    #pragma unroll
    for (int i = 0; i < 512; i += 64) {
      const int col = st8 + i;
      *(bf16x8*)(sAB + sr * 1024 + ((2 * col) ^ xrs)) =
          *(const bf16x8*)(aRow + kbase + col);
    }
    __syncthreads();
    for (int it = 0; it < 16; ++it) {
      bf16x8 bg = pack8(cg0, cg1);
      bf16x8 bu = pack8(cu0, cu1);
      if (hh == 0 || it < 15) {
        const int nit = it + 1;
        const int kcn = (nit < 16) ? kbase + ((nit + ph) & 15) * 32
                                   : (half ^ 1) * 512 + ph * 32;
        cg0 = *(const floatx4*)(wgR + kcn + kq);
        cg1 = *(const floatx4*)(wgR + kcn + kq + 4);
        cu0 = *(const floatx4*)(wuR + kcn + kq);
        cu1 = *(const floatx4*)(wuR + kcn + kq + 4);
      }
      const int kcl = ((it + ph) & 15) * 32;
      const int kb = 2 * (kcl + kq);
      bf16x8 a0 = *(const bf16x8*)(sAB + c * 1024 + (kb ^ xr0));
      bf16x8 a1 = *(const bf16x8*)(sAB + (16 + c) * 1024 + (kb ^ xr0));
      ag0 = mfma16(a0, bg, ag0);
      ag1 = mfma16(a1, bg, ag1);
      au0 = mfma16(a0, bu, au0);
      au1 = mfma16(a1, bu, au1);
    }
  }
  #pragma unroll
  for (int s = 0; s < 2; ++s) {
    floatx4 g = s ? ag1 : ag0;
    floatx4 u = s ? au1 : au0;
    #pragma unroll
    for (int r = 0; r < 4; ++r) {
      const int m = m0 + s * 16 + q * 4 + r;
      float gg = g[r], uu = u[r];
      float a = gg / (1.0f + __expf(-gg)) * uu;
      act_s[(size_t)m * SI_DIM + n0 + wv * 16 + c] = f2bf(a);
    }
  }
}

// ---------------------------------------------------------------------------
// Kernel 4: shared down; K-split x2 across blocks, rotated, atomicAdd out.
// ---------------------------------------------------------------------------
__global__ __launch_bounds__(256, 2) void shared_down_kernel(
    const unsigned short* __restrict__ act_s, const float* __restrict__ wsd,
    float* __restrict__ out) {
  __shared__ __align__(16) char sAB[BM * 1024];

  const int bid = blockIdx.x;
  const int n0 = (bid & 15) * BN;
  const int m0 = ((bid >> 4) & 7) * BM;
  const int kh = bid >> 7;
  const int kbeg = kh * (SI_DIM / 2);
  const int j = threadIdx.x;
  const int wv = j >> 6, lane = j & 63;
  const int q = lane >> 4, c = lane & 15;
  const int kq = q * 8;

  const float* wR = wsd + (size_t)(n0 + wv * 16 + c) * SI_DIM + kbeg;

  const int sr = j >> 3, st8 = (j & 7) * 8;
  const int xrs = (sr & 7) << 4;
  const int xr0 = (c & 7) << 4;
  const unsigned short* aRow = act_s + (size_t)(m0 + sr) * SI_DIM + kbeg;

  const int h0 = bid & 1;
  const int ph = ((bid * 5) + (wv * 7)) & 15;

  floatx4 cw0, cw1;
  {
    const int kc = h0 * 512 + ph * 32;
    cw0 = *(const floatx4*)(wR + kc + kq);
    cw1 = *(const floatx4*)(wR + kc + kq + 4);
  }

  floatx4 ac0 = (floatx4)0.0f, ac1 = (floatx4)0.0f;
  for (int hh = 0; hh < 2; ++hh) {
    const int half = h0 ^ hh;
    const int kbase = half * 512;
    __syncthreads();
    #pragma unroll
    for (int i = 0; i < 512; i += 64) {
      const int col = st8 + i;
      *(bf16x8*)(sAB + sr * 1024 + ((2 * col) ^ xrs)) =
          *(const bf16x8*)(aRow + kbase + col);
    }
    __syncthreads();
    for (int it = 0; it < 16; ++it) {
      bf16x8 b = pack8(cw0, cw1);
      if (hh == 0 || it < 15) {
        const int nit = it + 1;
        const int kcn = (nit < 16) ? kbase + ((nit + ph) & 15) * 32
                                   : (half ^ 1) * 512 + ph * 32;
        cw0 = *(const floatx4*)(wR + kcn + kq);
        cw1 = *(const floatx4*)(wR + kcn + kq + 4);
      }
      const int kcl = ((it + ph) & 15) * 32;
      const int kb = 2 * (kcl + kq);
      bf16x8 a0 = *(const bf16x8*)(sAB + c * 1024 + (kb ^ xr0));
      bf16x8 a1 = *(const bf16x8*)(sAB + (16 + c) * 1024 + (kb ^ xr0));
      ac0 = mfma16(a0, b, ac0);
      ac1 = mfma16(a1, b, ac1);
    }
  }
  #pragma unroll
  for (int s = 0; s < 2; ++s) {
    floatx4 d = s ? ac1 : ac0;
    #pragma unroll
    for (int r = 0; r < 4; ++r) {
      const int m = m0 + s * 16 + q * 4 + r;
      atomicAdd(&out[(size_t)m * H_DIM + n0 + wv * 16 + c], d[r]);
    }
  }
}

// ---------------------------------------------------------------------------
// Kernel 5: routed down + weighted scatter-add, rotated direct-stream
// (w2 rows = 2 KB stride => same camping fix; 16 chunks, no halves).
// ---------------------------------------------------------------------------
__global__ __launch_bounds__(256, 2) void routed_down_kernel(
    const unsigned short* __restrict__ act_r, const float* __restrict__ w2,
    const int* __restrict__ cnt, const int* __restrict__ tok_list,
    const float* __restrict__ wt_list, float* __restrict__ out) {
  __shared__ __align__(16) char sAB[BM * 1024];  // 32 x 512 bf16, swizzled

  const int bid = blockIdx.x;
  const int e = bid >> 4;
  const int n0 = (bid & 15) * BN;
  const int j = threadIdx.x;
  const int wv = j >> 6, lane = j & 63;
  const int q = lane >> 4, c = lane & 15;
  const int kq = q * 8;
  const int ne = cnt[e];
  if (ne <= 0) return;
  const int* tl = tok_list + e * T_TOK;
  const float* wl = wt_list + e * T_TOK;
  const unsigned short* apb = act_r + (size_t)e * T_TOK * I_DIM;
  const float* wR = w2 + ((size_t)e * H_DIM + n0 + wv * 16 + c) * I_DIM;

  const int sr = j >> 3, st8 = (j & 7) * 8;
  const int xrs = (sr & 7) << 4;
  const int xr0 = (c & 7) << 4;

  const int ph = ((bid * 5) + (wv * 7)) & 15;

  for (int m0 = 0; m0 < ne; m0 += BM) {
    floatx4 cw0, cw1;
    {
      const int kc = ph * 32;
      cw0 = *(const floatx4*)(wR + kc + kq);
      cw1 = *(const floatx4*)(wR + kc + kq + 4);
    }
    __syncthreads();
    {
      int ar = m0 + sr;
      if (ar >= ne) ar = m0;      // pad rows re-stage a valid row
      const unsigned short* aRow = apb + (size_t)ar * I_DIM;
      #pragma unroll
      for (int i = 0; i < I_DIM; i += 64) {
        const int col = st8 + i;
        *(bf16x8*)(sAB + sr * 1024 + ((2 * col) ^ xrs)) =
            *(const bf16x8*)(aRow + col);
      }
    }
    __syncthreads();

    floatx4 ac0 = (floatx4)0.0f, ac1 = (floatx4)0.0f;
    for (int it = 0; it < 16; ++it) {
      bf16x8 b = pack8(cw0, cw1);
      if (it < 15) {
        const int kcn = ((it + 1 + ph) & 15) * 32;
        cw0 = *(const floatx4*)(wR + kcn + kq);
        cw1 = *(const floatx4*)(wR + kcn + kq + 4);
      }
      const int kcl = ((it + ph) & 15) * 32;
      const int kb = 2 * (kcl + kq);
      bf16x8 a0 = *(const bf16x8*)(sAB + c * 1024 + (kb ^ xr0));
      bf16x8 a1 = *(const bf16x8*)(sAB + (16 + c) * 1024 + (kb ^ xr0));
      ac0 = mfma16(a0, b, ac0);
      ac1 = mfma16(a1, b, ac1);
    }
    #pragma unroll
    for (int s = 0; s < 2; ++s) {
      floatx4 d = s ? ac1 : ac0;
      #pragma unroll
      for (int r = 0; r < 4; ++r) {
        const int mi = s * 16 + q * 4 + r;
        if (m0 + mi < ne) {
          atomicAdd(&out[(size_t)tl[m0 + mi] * H_DIM + n0 + wv * 16 + c],
                    d[r] * wl[m0 + mi]);
        }
      }
    }
  }
}

extern "C" void kernel_launch(void* const* d_in, const int* in_sizes, int n_in,
                              void* d_out, int out_size, void* d_ws, size_t ws_size,
                              hipStream_t stream) {
  const float* x   = (const float*)d_in[0];
  const float* gw  = (const float*)d_in[1];
  const float* eb  = (const float*)d_in[2];
  const float* w1  = (const float*)d_in[3];
  const float* w3  = (const float*)d_in[4];
  const float* w2  = (const float*)d_in[5];
  const float* wsg = (const float*)d_in[6];
  const float* wsu = (const float*)d_in[7];
  const float* wsd = (const float*)d_in[8];
  float* out = (float*)d_out;

  char* ws = (char*)d_ws;
  unsigned short* xbf   = (unsigned short*)(ws);                 // 512 KB
  unsigned short* act_s = (unsigned short*)(ws + 524288);        // 1 MB
  int*   cnt            = (int*)(ws + 1572864);                  // 256 B
  int*   tok            = (int*)(ws + 1573120);                  // 64 KB
  float* wt             = (float*)(ws + 1638656);                // 64 KB
  unsigned short* act_r = (unsigned short*)(ws + 1704192);       // 16.8 MB

  hipMemsetAsync(cnt, 0, E_NUM * sizeof(int), stream);
  hipMemsetAsync(out, 0, (size_t)T_TOK * H_DIM * sizeof(float), stream);
  gate_route_kernel<<<dim3(T_TOK), dim3(256), 0, stream>>>(x, gw, eb, xbf, cnt, tok, wt);
  routed_gu_kernel<<<dim3(E_NUM * (I_DIM / BN)), dim3(256), 0, stream>>>(xbf, w1, w3, cnt, tok, act_r);
  shared_gu_kernel<<<dim3((SI_DIM / BN) * (T_TOK / BM)), dim3(256), 0, stream>>>(xbf, wsg, wsu, act_s);
  shared_down_kernel<<<dim3((H_DIM / BN) * (T_TOK / BM) * 2), dim3(256), 0, stream>>>(act_s, wsd, out);
  routed_down_kernel<<<dim3(E_NUM * (H_DIM / BN)), dim3(256), 0, stream>>>(act_r, w2, cnt, tok, wt, out);
}

// Round 7
// 448.827 us; speedup vs baseline: 1.0709x; 1.0369x over previous
//
#include <hip/hip_runtime.h>
#include <math.h>

#define T_TOK 256
#define H_DIM 1024
#define E_NUM 64
#define I_DIM 512
#define SI_DIM 2048
#define TK 256

typedef __attribute__((ext_vector_type(8))) __bf16 bf16x8;
typedef __attribute__((ext_vector_type(4))) float floatx4;
typedef __attribute__((ext_vector_type(4))) unsigned short ushort4v;

// float -> bf16 round-to-nearest-even
static __device__ __forceinline__ unsigned short f2bf(float f) {
  unsigned u = __float_as_uint(f);
  u += 0x7FFFu + ((u >> 16) & 1u);
  return (unsigned short)(u >> 16);
}

static __device__ __forceinline__ ushort4v pack4(floatx4 v) {
  ushort4v b;
  b[0] = f2bf(v[0]); b[1] = f2bf(v[1]); b[2] = f2bf(v[2]); b[3] = f2bf(v[3]);
  return b;
}

static __device__ __forceinline__ floatx4 mfma16(bf16x8 a, bf16x8 b, floatx4 c) {
  return __builtin_amdgcn_mfma_f32_16x16x32_bf16(a, b, c, 0, 0, 0);
}

// ---------------------------------------------------------------------------
// Kernel 1: gate matmul (fp64, 4-way H-split) + noaux_tc routing + x->bf16.
// ---------------------------------------------------------------------------
__global__ __launch_bounds__(256) void gate_route_kernel(
    const float* __restrict__ x, const float* __restrict__ gw,
    const float* __restrict__ ebias, unsigned short* __restrict__ xbf,
    int* __restrict__ cnt, int* __restrict__ tok_list,
    float* __restrict__ wt_list) {
  const int t = blockIdx.x;
  const int j = threadIdx.x;
  __shared__ float xs[H_DIM];
  __shared__ double pd[4 * 64];

  floatx4 v = ((const floatx4*)(x + (size_t)t * H_DIM))[j];
  xs[4 * j + 0] = v[0]; xs[4 * j + 1] = v[1];
  xs[4 * j + 2] = v[2]; xs[4 * j + 3] = v[3];
  ((ushort4v*)(xbf + (size_t)t * H_DIM))[j] = pack4(v);
  __syncthreads();

  const int e = j & 63, ch = j >> 6;
  const float* wr = gw + (size_t)e * H_DIM + ch * 256;
  const float* xc = xs + ch * 256;
  double acc = 0.0;
  for (int i = 0; i < 64; ++i) {
    floatx4 w = ((const floatx4*)wr)[i];
    acc += (double)xc[4 * i + 0] * (double)w[0]
         + (double)xc[4 * i + 1] * (double)w[1]
         + (double)xc[4 * i + 2] * (double)w[2]
         + (double)xc[4 * i + 3] * (double)w[3];
  }
  pd[ch * 64 + e] = acc;
  __syncthreads();

  if (j < 64) {
    const int lane = j;
    const double logit = pd[lane] + pd[64 + lane] + pd[128 + lane] + pd[192 + lane];
    const double score = 1.0 / (1.0 + exp(-logit));
    const double swb = score + (double)ebias[lane];

    double m1 = swb, m2 = -1.0e300;
    #pragma unroll
    for (int d = 1; d < 8; d <<= 1) {
      double o1 = __shfl_xor(m1, d);
      double o2 = __shfl_xor(m2, d);
      double hi = fmax(m1, o1), lo = fmin(m1, o1);
      m1 = hi;
      m2 = fmax(lo, fmax(m2, o2));
    }
    const double gscore = m1 + m2;

    double gs[8];
    #pragma unroll
    for (int g = 0; g < 8; ++g) gs[g] = __shfl(gscore, g << 3);
    unsigned gsel = 0;
    #pragma unroll
    for (int it = 0; it < 4; ++it) {
      int best = 0; double bv = -1.0e300;
      #pragma unroll
      for (int g = 0; g < 8; ++g) {
        bool taken = (gsel >> g) & 1u;
        if (!taken && gs[g] > bv) { bv = gs[g]; best = g; }
      }
      gsel |= 1u << best;
    }

    double key = ((gsel >> (lane >> 3)) & 1u) ? swb : -1.0e300;
    int selected = 0;
    for (int it = 0; it < 6; ++it) {
      double vv = key; int idx = lane;
      #pragma unroll
      for (int d = 1; d < 64; d <<= 1) {
        double ov = __shfl_xor(vv, d);
        int oi = __shfl_xor(idx, d);
        if (ov > vv || (ov == vv && oi < idx)) { vv = ov; idx = oi; }
      }
      if (lane == idx) { selected = 1; key = -1.0e300; }
    }

    double ssum = selected ? score : 0.0;
    #pragma unroll
    for (int d = 1; d < 64; d <<= 1) ssum += __shfl_xor(ssum, d);

    if (selected) {
      float wgt = (float)(score / (ssum + 1e-20) * 2.5);
      int p = atomicAdd(&cnt[lane], 1);
      tok_list[lane * T_TOK + p] = t;
      wt_list[lane * T_TOK + p] = wgt;
    }
  }
}

// ---------------------------------------------------------------------------
// Kernel 2: routed gate/up, PAGE-SEQUENTIAL weight staging.
// Each wave-instruction reads 1 KB contiguous (64 lanes x 16B) of ONE weight
// row; 8 such loads issue back-to-back per batch. Weights land bf16-packed in
// swizzled LDS; MFMA B-frags read conflict-light b128. A (tokens) read
// per-lane from L2-resident xbf. BN=32, BM=64 (wave-split), TK=256.
// ---------------------------------------------------------------------------
__global__ __launch_bounds__(256, 4) void routed_gu_kernel(
    const unsigned short* __restrict__ xbf, const float* __restrict__ w1,
    const float* __restrict__ w3, const int* __restrict__ cnt,
    const int* __restrict__ tok_list, unsigned short* __restrict__ act_r) {
  __shared__ __align__(16) char sW[2 * 32 * 512];  // [mat][32 rows][256 bf16], 32 KB

  const int bid = blockIdx.x;
  const int e = bid >> 4;
  const int n0 = (bid & 15) * 32;
  const int j = threadIdx.x;
  const int wv = j >> 6, lane = j & 63;
  const int q = lane >> 4, c = lane & 15;
  const int kq = q * 8;
  const int ne = cnt[e];
  if (ne <= 0) return;
  const int* tl = tok_list + e * T_TOK;
  unsigned short* ap = act_r + (size_t)e * T_TOK * I_DIM;

  const float* w1g = w1 + ((size_t)e * I_DIM + n0) * H_DIM;
  const float* w3g = w3 + ((size_t)e * I_DIM + n0) * H_DIM;
  const int x0 = (c & 7) << 4;

  for (int m0 = 0; m0 < ne; m0 += 64) {
    int ti = m0 + wv * 16 + c; if (ti > ne - 1) ti = ne - 1;
    const unsigned short* aP = xbf + (size_t)tl[ti] * H_DIM;

    floatx4 ag0 = (floatx4)0.f, ag1 = (floatx4)0.f;
    floatx4 au0 = (floatx4)0.f, au1 = (floatx4)0.f;

    for (int kt = 0; kt < H_DIM; kt += TK) {
      __syncthreads();  // prior readers of sW done
      #pragma unroll
      for (int b = 0; b < 2; ++b) {
        floatx4 f[8];
        #pragma unroll
        for (int t = 0; t < 8; ++t) {
          const int id = wv * 16 + b * 8 + t;
          const float* base = (id < 32) ? w1g : w3g;
          f[t] = *(const floatx4*)(base + (size_t)(id & 31) * H_DIM + kt + lane * 4);
        }
        #pragma unroll
        for (int t = 0; t < 8; ++t) {
          const int id = wv * 16 + b * 8 + t;
          const int rl = id & 31;
          *(ushort4v*)(sW + (id >> 5) * 16384 + rl * 512 +
                       ((lane * 8) ^ ((rl & 7) << 4))) = pack4(f[t]);
        }
      }
      __syncthreads();
      for (int kcl = 0; kcl < TK; kcl += 32) {
        bf16x8 a = *(const bf16x8*)(aP + kt + kcl + kq);
        const int kb = 2 * (kcl + kq);
        bf16x8 bg0 = *(const bf16x8*)(sW + c * 512 + (kb ^ x0));
        bf16x8 bg1 = *(const bf16x8*)(sW + (16 + c) * 512 + (kb ^ x0));
        bf16x8 bu0 = *(const bf16x8*)(sW + 16384 + c * 512 + (kb ^ x0));
        bf16x8 bu1 = *(const bf16x8*)(sW + 16384 + (16 + c) * 512 + (kb ^ x0));
        ag0 = mfma16(a, bg0, ag0);
        ag1 = mfma16(a, bg1, ag1);
        au0 = mfma16(a, bu0, au0);
        au1 = mfma16(a, bu1, au1);
      }
    }
    #pragma unroll
    for (int r = 0; r < 4; ++r) {
      const int m = m0 + wv * 16 + q * 4 + r;
      if (m < ne) {
        float g0 = ag0[r], u0 = au0[r];
        float g1 = ag1[r], u1 = au1[r];
        ap[(size_t)m * I_DIM + n0 + c] = f2bf(g0 / (1.f + __expf(-g0)) * u0);
        ap[(size_t)m * I_DIM + n0 + 16 + c] = f2bf(g1 / (1.f + __expf(-g1)) * u1);
      }
    }
  }
}

// ---------------------------------------------------------------------------
// Kernel 3: shared gate/up, same page-sequential staging. BM=64 halves the
// weight re-reads vs BM=32 (134 -> 67 MB).
// ---------------------------------------------------------------------------
__global__ __launch_bounds__(256, 4) void shared_gu_kernel(
    const unsigned short* __restrict__ xbf, const float* __restrict__ wsg,
    const float* __restrict__ wsu, unsigned short* __restrict__ act_s) {
  __shared__ __align__(16) char sW[2 * 32 * 512];

  const int bid = blockIdx.x;
  const int n0 = (bid & 63) * 32;
  const int m0 = (bid >> 6) * 64;
  const int j = threadIdx.x;
  const int wv = j >> 6, lane = j & 63;
  const int q = lane >> 4, c = lane & 15;
  const int kq = q * 8;

  const float* wgg = wsg + (size_t)n0 * H_DIM;
  const float* wug = wsu + (size_t)n0 * H_DIM;
  const int x0 = (c & 7) << 4;
  const unsigned short* aP = xbf + (size_t)(m0 + wv * 16 + c) * H_DIM;

  floatx4 ag0 = (floatx4)0.f, ag1 = (floatx4)0.f;
  floatx4 au0 = (floatx4)0.f, au1 = (floatx4)0.f;

  for (int kt = 0; kt < H_DIM; kt += TK) {
    __syncthreads();
    #pragma unroll
    for (int b = 0; b < 2; ++b) {
      floatx4 f[8];
      #pragma unroll
      for (int t = 0; t < 8; ++t) {
        const int id = wv * 16 + b * 8 + t;
        const float* base = (id < 32) ? wgg : wug;
        f[t] = *(const floatx4*)(base + (size_t)(id & 31) * H_DIM + kt + lane * 4);
      }
      #pragma unroll
      for (int t = 0; t < 8; ++t) {
        const int id = wv * 16 + b * 8 + t;
        const int rl = id & 31;
        *(ushort4v*)(sW + (id >> 5) * 16384 + rl * 512 +
                     ((lane * 8) ^ ((rl & 7) << 4))) = pack4(f[t]);
      }
    }
    __syncthreads();
    for (int kcl = 0; kcl < TK; kcl += 32) {
      bf16x8 a = *(const bf16x8*)(aP + kt + kcl + kq);
      const int kb = 2 * (kcl + kq);
      bf16x8 bg0 = *(const bf16x8*)(sW + c * 512 + (kb ^ x0));
      bf16x8 bg1 = *(const bf16x8*)(sW + (16 + c) * 512 + (kb ^ x0));
      bf16x8 bu0 = *(const bf16x8*)(sW + 16384 + c * 512 + (kb ^ x0));
      bf16x8 bu1 = *(const bf16x8*)(sW + 16384 + (16 + c) * 512 + (kb ^ x0));
      ag0 = mfma16(a, bg0, ag0);
      ag1 = mfma16(a, bg1, ag1);
      au0 = mfma16(a, bu0, au0);
      au1 = mfma16(a, bu1, au1);
    }
  }
  #pragma unroll
  for (int r = 0; r < 4; ++r) {
    const int m = m0 + wv * 16 + q * 4 + r;
    float g0 = ag0[r], u0 = au0[r];
    float g1 = ag1[r], u1 = au1[r];
    act_s[(size_t)m * SI_DIM + n0 + c] = f2bf(g0 / (1.f + __expf(-g0)) * u0);
    act_s[(size_t)m * SI_DIM + n0 + 16 + c] = f2bf(g1 / (1.f + __expf(-g1)) * u1);
  }
}

// ---------------------------------------------------------------------------
// Kernel 4: shared down; K-split x2 across blocks, page-sequential staging,
// atomicAdd into zeroed out.
// ---------------------------------------------------------------------------
__global__ __launch_bounds__(256, 4) void shared_down_kernel(
    const unsigned short* __restrict__ act_s, const float* __restrict__ wsd,
    float* __restrict__ out) {
  __shared__ __align__(16) char sW[32 * 512];  // 16 KB

  const int bid = blockIdx.x;
  const int n0 = (bid & 31) * 32;
  const int m0 = ((bid >> 5) & 3) * 64;
  const int kh = bid >> 7;
  const int k0 = kh * (SI_DIM / 2);
  const int j = threadIdx.x;
  const int wv = j >> 6, lane = j & 63;
  const int q = lane >> 4, c = lane & 15;
  const int kq = q * 8;

  const float* wg = wsd + (size_t)n0 * SI_DIM + k0;
  const int x0 = (c & 7) << 4;
  const unsigned short* aP = act_s + (size_t)(m0 + wv * 16 + c) * SI_DIM + k0;

  floatx4 ac0 = (floatx4)0.f, ac1 = (floatx4)0.f;

  for (int kt = 0; kt < SI_DIM / 2; kt += TK) {
    __syncthreads();
    {
      floatx4 f[8];
      #pragma unroll
      for (int t = 0; t < 8; ++t) {
        const int id = wv * 8 + t;
        f[t] = *(const floatx4*)(wg + (size_t)id * SI_DIM + kt + lane * 4);
      }
      #pragma unroll
      for (int t = 0; t < 8; ++t) {
        const int id = wv * 8 + t;
        *(ushort4v*)(sW + id * 512 + ((lane * 8) ^ ((id & 7) << 4))) = pack4(f[t]);
      }
    }
    __syncthreads();
    for (int kcl = 0; kcl < TK; kcl += 32) {
      bf16x8 a = *(const bf16x8*)(aP + kt + kcl + kq);
      const int kb = 2 * (kcl + kq);
      bf16x8 b0 = *(const bf16x8*)(sW + c * 512 + (kb ^ x0));
      bf16x8 b1 = *(const bf16x8*)(sW + (16 + c) * 512 + (kb ^ x0));
      ac0 = mfma16(a, b0, ac0);
      ac1 = mfma16(a, b1, ac1);
    }
  }
  #pragma unroll
  for (int r = 0; r < 4; ++r) {
    const int m = m0 + wv * 16 + q * 4 + r;
    atomicAdd(&out[(size_t)m * H_DIM + n0 + c], ac0[r]);
    atomicAdd(&out[(size_t)m * H_DIM + n0 + 16 + c], ac1[r]);
  }
}

// ---------------------------------------------------------------------------
// Kernel 5: routed down + weighted scatter-add, page-sequential staging.
// ---------------------------------------------------------------------------
__global__ __launch_bounds__(256, 4) void routed_down_kernel(
    const unsigned short* __restrict__ act_r, const float* __restrict__ w2,
    const int* __restrict__ cnt, const int* __restrict__ tok_list,
    const float* __restrict__ wt_list, float* __restrict__ out) {
  __shared__ __align__(16) char sW[32 * 512];  // 16 KB

  const int bid = blockIdx.x;
  const int e = bid >> 5;
  const int n0 = (bid & 31) * 32;
  const int j = threadIdx.x;
  const int wv = j >> 6, lane = j & 63;
  const int q = lane >> 4, c = lane & 15;
  const int kq = q * 8;
  const int ne = cnt[e];
  if (ne <= 0) return;
  const int* tl = tok_list + e * T_TOK;
  const float* wl = wt_list + e * T_TOK;
  const unsigned short* apb = act_r + (size_t)e * T_TOK * I_DIM;
  const float* wg = w2 + ((size_t)e * H_DIM + n0) * I_DIM;
  const int x0 = (c & 7) << 4;

  for (int m0 = 0; m0 < ne; m0 += 64) {
    int mi_ = m0 + wv * 16 + c; if (mi_ > ne - 1) mi_ = ne - 1;
    const unsigned short* aP = apb + (size_t)mi_ * I_DIM;

    floatx4 ac0 = (floatx4)0.f, ac1 = (floatx4)0.f;

    for (int kt = 0; kt < I_DIM; kt += TK) {
      __syncthreads();
      {
        floatx4 f[8];
        #pragma unroll
        for (int t = 0; t < 8; ++t) {
          const int id = wv * 8 + t;
          f[t] = *(const floatx4*)(wg + (size_t)id * I_DIM + kt + lane * 4);
        }
        #pragma unroll
        for (int t = 0; t < 8; ++t) {
          const int id = wv * 8 + t;
          *(ushort4v*)(sW + id * 512 + ((lane * 8) ^ ((id & 7) << 4))) = pack4(f[t]);
        }
      }
      __syncthreads();
      for (int kcl = 0; kcl < TK; kcl += 32) {
        bf16x8 a = *(const bf16x8*)(aP + kt + kcl + kq);
        const int kb = 2 * (kcl + kq);
        bf16x8 b0 = *(const bf16x8*)(sW + c * 512 + (kb ^ x0));
        bf16x8 b1 = *(const bf16x8*)(sW + (16 + c) * 512 + (kb ^ x0));
        ac0 = mfma16(a, b0, ac0);
        ac1 = mfma16(a, b1, ac1);
      }
    }
    #pragma unroll
    for (int r = 0; r < 4; ++r) {
      const int m = m0 + wv * 16 + q * 4 + r;
      if (m < ne) {
        const float w = wl[m];
        float* o = out + (size_t)tl[m] * H_DIM + n0;
        atomicAdd(o + c, ac0[r] * w);
        atomicAdd(o + 16 + c, ac1[r] * w);
      }
    }
  }
}

extern "C" void kernel_launch(void* const* d_in, const int* in_sizes, int n_in,
                              void* d_out, int out_size, void* d_ws, size_t ws_size,
                              hipStream_t stream) {
  const float* x   = (const float*)d_in[0];
  const float* gw  = (const float*)d_in[1];
  const float* eb  = (const float*)d_in[2];
  const float* w1  = (const float*)d_in[3];
  const float* w3  = (const float*)d_in[4];
  const float* w2  = (const float*)d_in[5];
  const float* wsg = (const float*)d_in[6];
  const float* wsu = (const float*)d_in[7];
  const float* wsd = (const float*)d_in[8];
  float* out = (float*)d_out;

  char* ws = (char*)d_ws;
  unsigned short* xbf   = (unsigned short*)(ws);                 // 512 KB
  unsigned short* act_s = (unsigned short*)(ws + 524288);        // 1 MB
  int*   cnt            = (int*)(ws + 1572864);                  // 256 B
  int*   tok            = (int*)(ws + 1573120);                  // 64 KB
  float* wt             = (float*)(ws + 1638656);                // 64 KB
  unsigned short* act_r = (unsigned short*)(ws + 1704192);       // 16.8 MB

  hipMemsetAsync(cnt, 0, E_NUM * sizeof(int), stream);
  hipMemsetAsync(out, 0, (size_t)T_TOK * H_DIM * sizeof(float), stream);
  gate_route_kernel<<<dim3(T_TOK), dim3(256), 0, stream>>>(x, gw, eb, xbf, cnt, tok, wt);
  routed_gu_kernel<<<dim3(E_NUM * (I_DIM / 32)), dim3(256), 0, stream>>>(xbf, w1, w3, cnt, tok, act_r);
  shared_gu_kernel<<<dim3((SI_DIM / 32) * (T_TOK / 64)), dim3(256), 0, stream>>>(xbf, wsg, wsu, act_s);
  shared_down_kernel<<<dim3(32 * 4 * 2), dim3(256), 0, stream>>>(act_s, wsd, out);
  routed_down_kernel<<<dim3(E_NUM * (H_DIM / 32)), dim3(256), 0, stream>>>(act_r, w2, cnt, tok, wt, out);
}